// Round 13
// baseline (137.440 us; speedup 1.0000x reference)
//
#include <hip/hip_runtime.h>
#include <math.h>
#include <stddef.h>

#define LQ 2048
#define DM 1024
#define NH 16
#define DH 64
#define LR 4095  // 2*LQ-1

typedef __attribute__((ext_vector_type(4))) float f4v;
typedef __attribute__((ext_vector_type(8))) short s8v;
typedef __attribute__((ext_vector_type(2))) unsigned short us2;
typedef __attribute__((ext_vector_type(8))) unsigned short us8;
typedef __attribute__((ext_vector_type(2))) unsigned int u32x2;
typedef __attribute__((ext_vector_type(4))) unsigned int u32x4;

__device__ __forceinline__ unsigned short f2bf(float x) {
    unsigned int u = __float_as_uint(x);
    return (unsigned short)((u + 0x7FFFu + ((u >> 16) & 1u)) >> 16);
}
__device__ __forceinline__ float bf2f(unsigned short s) {
    return __uint_as_float(((unsigned int)s) << 16);
}
__device__ __forceinline__ unsigned cvtpk(float lo, float hi) {
    unsigned r;
    asm("v_cvt_pk_bf16_f32 %0, %1, %2" : "=v"(r) : "v"(lo), "v"(hi));
    return r;
}
#define GLOAD16(g, l) __builtin_amdgcn_global_load_lds((g), (l), 16, 0, 0)
// fence for cross-lane LDS handoff within a wave (load-bearing! r5 NaN)
#define WAVE_LDS_FENCE() do { \
    asm volatile("s_waitcnt lgkmcnt(0)" ::: "memory"); \
    __builtin_amdgcn_sched_barrier(0); } while (0)

#define MFMA16(a, b, c) __builtin_amdgcn_mfma_f32_16x16x32_bf16((a), (b), (c), 0, 0, 0)

// swizzled read from linear-DMA-staged tile: byte ^= (row&7)<<4 (source was
// pre-swizzled col c8^(row&7), so this recovers global[row][colshort/8])
__device__ __forceinline__ s8v sw_read8(const unsigned short* base, int row, int colshort) {
    int byte = (row * 128 + colshort * 2) ^ ((row & 7) << 4);
    return *(const s8v*)((const char*)base + byte);
}

// ---------------------------------------------------------------------------
// prep: [0,3072) cast f32->bf16 [w|Wq|Wk|Wv|Wr]; [3072,11262) sinusoid r;
// [11262,11390) zero the 128-row guards around rp.
// ---------------------------------------------------------------------------
__global__ __launch_bounds__(256)
void prep(const float* __restrict__ w, const float* __restrict__ Wq,
          const float* __restrict__ Wk, const float* __restrict__ Wv,
          const float* __restrict__ Wr, unsigned short* __restrict__ dst,
          unsigned short* __restrict__ r, unsigned short* __restrict__ rpg) {
    int b = blockIdx.x;
    if (b < 3072) {
        size_t e0 = ((size_t)b * 256 + threadIdx.x) * 8;
        const float* src;
        if (e0 < (size_t)LQ * DM) src = w + e0;
        else {
            size_t ro = e0 - (size_t)LQ * DM;
            int wi = (int)(ro >> 20);
            size_t off = ro & 1048575;
            src = (wi == 0 ? Wq : wi == 1 ? Wk : wi == 2 ? Wv : Wr) + off;
        }
        f4v a = *(const f4v*)src;
        f4v c = *(const f4v*)(src + 4);
        us8 o;
        o[0]=f2bf(a[0]); o[1]=f2bf(a[1]); o[2]=f2bf(a[2]); o[3]=f2bf(a[3]);
        o[4]=f2bf(c[0]); o[5]=f2bf(c[1]); o[6]=f2bf(c[2]); o[7]=f2bf(c[3]);
        *(us8*)(dst + e0) = o;
    } else if (b < 11262) {
        int tg = (b - 3072) * 256 + threadIdx.x;   // LR*512 exactly
        int gm = tg >> 9, c2 = tg & 511;
        float invf = expf(-(float)c2 * (9.210340371976184f / 512.0f));
        float ang = (float)(gm - (LQ - 1)) * invf;
        float sv, cv;
        sincosf(ang, &sv, &cv);
        us2 o; o[0] = f2bf(sv); o[1] = f2bf(cv);
        *(us2*)&r[(size_t)gm * DM + c2 * 2] = o;
    } else {
        int idx = (b - 11262) * 2048 + threadIdx.x * 8;  // [0, 262144)
        unsigned short* p = (idx < 131072)
            ? (rpg - 131072 + idx)
            : (rpg + (size_t)LR * DM + (idx - 131072));
        *(us8*)p = (us8){0,0,0,0,0,0,0,0};
    }
}

// ---------------------------------------------------------------------------
// All 4 projections, 128x128 tile (m97 geometry), BK=64, global_load_lds(16),
// linear LDS, 4 waves each owning a 64x64 quadrant (4x4 frags).
// blocks [0,384): QKV (mat = bid>>7); [384,640): rp (mat=3).
// mat==2 writes C transposed (vt[n][m]) via an LDS-transpose epilogue so the
// global stores are coalesced us8 rows.
// ---------------------------------------------------------------------------
__global__ __launch_bounds__(256)
void proj_all(const unsigned short* __restrict__ wbf, const unsigned short* __restrict__ rr,
              const unsigned short* __restrict__ Wqb, const unsigned short* __restrict__ Wkb,
              const unsigned short* __restrict__ Wvb, const unsigned short* __restrict__ Wrb,
              unsigned short* __restrict__ qb, unsigned short* __restrict__ kkb,
              unsigned short* __restrict__ vtg, unsigned short* __restrict__ rpg) {
    __shared__ unsigned short ldsbuf[2 * 128 * 64];
    unsigned short* As = ldsbuf;
    unsigned short* Bs = ldsbuf + 128 * 64;
    int bid = blockIdx.x;
    int mat, mblk, nblk;
    if (bid < 384) { mat = bid >> 7; int rm = bid & 127; mblk = rm >> 3; nblk = rm & 7; }
    else           { mat = 3; int rm = bid - 384; mblk = rm >> 3; nblk = rm & 7; }
    const int M = (mat < 3) ? LQ : LR;
    const unsigned short* A = (mat < 3) ? wbf : rr;
    const unsigned short* B = mat == 0 ? Wqb : mat == 1 ? Wkb : mat == 2 ? Wvb : Wrb;
    unsigned short* C = mat == 0 ? qb : mat == 1 ? kkb : mat == 2 ? vtg : rpg;
    const int m0 = mblk * 128, n0 = nblk * 128;
    const int t = threadIdx.x;
    const int w = t >> 6, lan16 = t & 15, lgrp = (t & 63) >> 4;
    const int wm = (w >> 1) * 64, wn = (w & 1) * 64;
    f4v acc[4][4] = {};

    for (int k0 = 0; k0 < DM; k0 += 64) {
        #pragma unroll
        for (int it = 0; it < 4; ++it) {
            int slot = it * 256 + t;
            int row = slot >> 3, c8 = slot & 7;
            int gm = m0 + row; if (gm > M - 1) gm = M - 1;
            GLOAD16(A + (size_t)gm * DM + k0 + c8 * 8,
                    (char*)As + (size_t)(it * 256 + (t & ~63)) * 16);
            GLOAD16(B + (size_t)(n0 + row) * DM + k0 + c8 * 8,
                    (char*)Bs + (size_t)(it * 256 + (t & ~63)) * 16);
        }
        __syncthreads();
        #pragma unroll
        for (int kk = 0; kk < 2; ++kk) {
            s8v aF[4], bF[4];
            #pragma unroll
            for (int i = 0; i < 4; ++i) {
                aF[i] = *(const s8v*)&As[(wm + i * 16 + lan16) * 64 + kk * 32 + lgrp * 8];
                bF[i] = *(const s8v*)&Bs[(wn + i * 16 + lan16) * 64 + kk * 32 + lgrp * 8];
            }
            #pragma unroll
            for (int i = 0; i < 4; ++i)
                #pragma unroll
                for (int j = 0; j < 4; ++j)
                    acc[i][j] = MFMA16(aF[i], bF[j], acc[i][j]);
        }
        __syncthreads();
    }
    if (mat != 2) {
        #pragma unroll
        for (int i = 0; i < 4; ++i)
            #pragma unroll
            for (int j = 0; j < 4; ++j)
                #pragma unroll
                for (int rg = 0; rg < 4; ++rg) {
                    int row = m0 + wm + i * 16 + lgrp * 4 + rg;
                    if (row < M)
                        C[(size_t)row * DM + n0 + wn + j * 16 + lan16] = f2bf(acc[i][j][rg]);
                }
    } else {
        // stage C^T in LDS ([128 n][128 m] bf16, byte ^= (n&7)<<4), then
        // coalesced us8 row stores to vt[n][m].
        unsigned short* Ct = ldsbuf;   // reuses As+Bs (dead after last barrier)
        #pragma unroll
        for (int i = 0; i < 4; ++i)
            #pragma unroll
            for (int j = 0; j < 4; ++j) {
                int n = wn + j * 16 + lan16;
                int mb = wm + i * 16 + lgrp * 4;
                int byte = (n * 256 + mb * 2) ^ ((n & 7) << 4);
                u32x2 pp;
                pp[0] = cvtpk(acc[i][j][0], acc[i][j][1]);
                pp[1] = cvtpk(acc[i][j][2], acc[i][j][3]);
                *(u32x2*)((char*)Ct + byte) = pp;
            }
        __syncthreads();
        #pragma unroll
        for (int it = 0; it < 8; ++it) {
            int slot = it * 256 + t;
            int n = slot >> 4, c8 = slot & 15;
            int byte = (n * 256 + c8 * 16) ^ ((n & 7) << 4);
            us8 v = *(const us8*)((const char*)Ct + byte);
            *(us8*)&C[(size_t)(n0 + n) * LQ + m0 + c8 * 8] = v;
        }
    }
}

// ---------------------------------------------------------------------------
// Fused rel-attention, SWAPPED-operand MFMA (S^T = K@QU^T, G^T = band@QV^T,
// O^T = V^T@P^T). Fragment layouts are A/B-symmetric so all staging reads and
// Q-fragments are unchanged from r12 — only mfma arg order flips. Softmax/P
// land lane-local (q = W+lan16): P stored once [q][j] (4 b64), read as PV
// B-operand (2 b128). G^T sheared via [q][cl] pitch-84 (5 b64 + u16 reads,
// conflict-free). Pipeline/barriers/staging identical to r12 (verified).
// ---------------------------------------------------------------------------
__global__ __launch_bounds__(256, 2)
void attn_mfma(const unsigned short* __restrict__ q, const unsigned short* __restrict__ kkg,
               const unsigned short* __restrict__ vtg, const unsigned short* __restrict__ rpg,
               const float* __restrict__ ub, const float* __restrict__ vb,
               float* __restrict__ out) {
    __shared__ unsigned short Kb[2][64 * 64];
    __shared__ unsigned short Bb[2][128 * 64];
    __shared__ unsigned short Vb[64 * 64];
    __shared__ unsigned short Gtw[4][16 * 84];   // G^T shear: [q-local][cl] pitch 84
    __shared__ unsigned short Ptw[4][16 * 72];   // P^T: [q-local][j] pitch 72

    // XCD swizzle: 512 = 8 x 64 (2 heads per XCD chunk)
    const int dd = blockIdx.x;
    const int f = (dd & 7) * 64 + (dd >> 3);
    const int h = f >> 5;
    const int i0 = (f & 31) * 64;
    const int col0 = h * DH;

    const int t = threadIdx.x;
    const int w = t >> 6, lan16 = t & 15, lgrp = (t & 63) >> 4;
    const int W = w * 16;
    const int cbase = 48 - W;
    const float C1 = 0.125f * 1.4426950408889634f;
    const float C0 = -4.0f * 1.4426950408889634f;

    unsigned short* gw = Gtw[w];
    unsigned short* pw = Ptw[w];

    // Q fragments direct from global + f32 bias (same data serves as swapped
    // B-operand: lane&15 -> q column, (lane>>4)*8+e -> k)
    union uv { u32x4 u; s8v s; };
    auto mkfrag = [&](int gi, const float* bias, s8v* dstf) {
        #pragma unroll
        for (int kk = 0; kk < 2; ++kk) {
            int cb = kk * 32 + lgrp * 8;
            us8 qv = (us8){0,0,0,0,0,0,0,0};
            if (gi < LQ) qv = *(const us8*)(q + (size_t)gi * DM + col0 + cb);
            f4v b0 = *(const f4v*)(bias + col0 + cb);
            f4v b1 = *(const f4v*)(bias + col0 + cb + 4);
            uv o;
            o.u[0] = cvtpk(bf2f(qv[0]) + b0[0], bf2f(qv[1]) + b0[1]);
            o.u[1] = cvtpk(bf2f(qv[2]) + b0[2], bf2f(qv[3]) + b0[3]);
            o.u[2] = cvtpk(bf2f(qv[4]) + b1[0], bf2f(qv[5]) + b1[1]);
            o.u[3] = cvtpk(bf2f(qv[6]) + b1[2], bf2f(qv[7]) + b1[3]);
            dstf[kk] = o.s;
        }
    };
    s8v quF[2], qvlF[2], qvsF[2];
    mkfrag(i0 + W + lan16, ub, quF);
    mkfrag(i0 + W + lan16, vb, qvlF);
    mkfrag(i0 + W + 1 + lan16, vb, qvsF);

    // DMA staging: linear LDS dest (wave base + lane*16), pre-swizzled source
    auto stageK = [&](int j0, int buf) {
        #pragma unroll
        for (int it = 0; it < 2; ++it) {
            int slot = it * 256 + t;
            int row = slot >> 3, c8 = (t & 7) ^ (row & 7);
            GLOAD16(kkg + (size_t)(j0 + row) * DM + col0 + c8 * 8,
                    (char*)&Kb[buf][0] + (size_t)(it * 256 + (t & ~63)) * 16);
        }
    };
    auto stageB = [&](int rel, int buf) {
        int base = (rel <= 0) ? rel + 4031 : rel - 65;
        #pragma unroll
        for (int it = 0; it < 4; ++it) {
            int slot = it * 256 + t;
            int row = slot >> 3, c8 = (t & 7) ^ (row & 7);
            GLOAD16(rpg + (ptrdiff_t)(base + row) * DM + col0 + c8 * 8,
                    (char*)&Bb[buf][0] + (size_t)(it * 256 + (t & ~63)) * 16);
        }
    };
    auto stageV = [&](int j0) {
        #pragma unroll
        for (int it = 0; it < 2; ++it) {
            int slot = it * 256 + t;
            int row = slot >> 3, c8 = (t & 7) ^ (row & 7);
            GLOAD16(vtg + (size_t)(col0 + row) * LQ + j0 + c8 * 8,
                    (char*)&Vb[0] + (size_t)(it * 256 + (t & ~63)) * 16);
        }
    };

    f4v accO[4] = {};
    float lsum = 0.f;

    stageK(0, 0);
    stageB(0 - i0, 0);

    // one j-tile; cur is a compile-time constant at each call site
    auto tile_body = [&](int tt, int cur) {
        const int j0 = tt * 64;
        const int rel = j0 - i0;
        stageV(j0);                                // 2 VMEM
        const int tn = (tt < 31) ? tt + 1 : 31;
        stageK(tn * 64, cur ^ 1);                  // 2 VMEM
        stageB(tn * 64 - i0, cur ^ 1);             // 4 VMEM
        __builtin_amdgcn_sched_barrier(0);
        asm volatile("s_waitcnt vmcnt(8)" ::: "memory");  // K/B of tile t done
        __builtin_amdgcn_s_barrier();
        __builtin_amdgcn_sched_barrier(0);

        // S^T = K @ QU^T : acF[nf][reg] = S^T[j = nf*16+lgrp*4+reg][q = W+lan16]
        __builtin_amdgcn_s_setprio(1);
        f4v acF[4] = {};
        #pragma unroll
        for (int nf = 0; nf < 4; ++nf)
            #pragma unroll
            for (int kk = 0; kk < 2; ++kk) {
                s8v bF = sw_read8(&Kb[cur][0], nf * 16 + lan16, kk * 32 + lgrp * 8);
                acF[nf] = MFMA16(bF, quF[kk], acF[nf]);
            }
        // G^T = band @ QV^T : g[c][reg] = G^T[cl = c*16+lgrp*4+reg][q = W+lan16]
        f4v g[5] = {};
        {
            const s8v* qf = (rel <= 0) ? qvlF : qvsF;
            #pragma unroll
            for (int c = 0; c < 5; ++c)
                #pragma unroll
                for (int kk = 0; kk < 2; ++kk) {
                    s8v bF = sw_read8(&Bb[cur][0], cbase + c * 16 + lan16, kk * 32 + lgrp * 8);
                    g[c] = MFMA16(bF, qf[kk], g[c]);
                }
        }
        __builtin_amdgcn_s_setprio(0);
        if (rel == 0) {   // diag tile: upper band direct from global (once/block)
            #pragma unroll
            for (int c = 0; c < 5; ++c) {
                int trow = -65 + cbase + c * 16 + lan16;
                const unsigned short* bp = rpg + (ptrdiff_t)trow * DM + col0;
                #pragma unroll
                for (int kk = 0; kk < 2; ++kk) {
                    us8 bv = *(const us8*)(bp + kk * 32 + lgrp * 8);
                    g[c] = MFMA16((s8v)bv, qvsF[kk], g[c]);
                }
            }
        }
        // G^T store: [q-local = lan16][cl] pitch 84, one b64 per c (cl-quad)
        #pragma unroll
        for (int c = 0; c < 5; ++c) {
            u32x2 pp;
            pp[0] = cvtpk(g[c][0], g[c][1]);
            pp[1] = cvtpk(g[c][2], g[c][3]);
            *(u32x2*)&gw[lan16 * 84 + c * 16 + lgrp * 4] = pp;
        }
        WAVE_LDS_FENCE();   // G stores -> softmax reads

        // softmax (swapped): lane owns q = W+lan16; shear read cl = j+15-lan16
        #pragma unroll
        for (int nf = 0; nf < 4; ++nf) {
            float pr[4];
            #pragma unroll
            for (int rg = 0; rg < 4; ++rg) {
                int j = nf * 16 + lgrp * 4 + rg;
                float bd = bf2f(gw[lan16 * 83 + j + 15]);
                pr[rg] = exp2f(fmaf(acF[nf][rg] + bd, C1, C0));
                lsum += pr[rg];
            }
            u32x2 pp;
            pp[0] = cvtpk(pr[0], pr[1]);
            pp[1] = cvtpk(pr[2], pr[3]);
            *(u32x2*)&pw[lan16 * 72 + nf * 16 + lgrp * 4] = pp;
        }
        WAVE_LDS_FENCE();   // P stores -> pF reads

        // pF = P^T B-operand: lane holds P[q = W+lan16][j = kk*32+lgrp*8+e]
        s8v pF[2];
        #pragma unroll
        for (int kk = 0; kk < 2; ++kk)
            pF[kk] = *(const s8v*)&pw[lan16 * 72 + kk * 32 + lgrp * 8];
        __builtin_amdgcn_sched_barrier(0);
        asm volatile("s_waitcnt vmcnt(6)" ::: "memory");  // V of tile t done
        __builtin_amdgcn_s_barrier();
        __builtin_amdgcn_sched_barrier(0);

        // O^T = V^T @ P^T : accO[nf][reg] = O^T[d = nf*16+lgrp*4+reg][q]
        __builtin_amdgcn_s_setprio(1);
        #pragma unroll
        for (int nf = 0; nf < 4; ++nf)
            #pragma unroll
            for (int kk = 0; kk < 2; ++kk) {
                s8v vF = sw_read8(&Vb[0], nf * 16 + lan16, kk * 32 + lgrp * 8);
                accO[nf] = MFMA16(vF, pF[kk], accO[nf]);
            }
        __builtin_amdgcn_s_setprio(0);
        __builtin_amdgcn_sched_barrier(0);
        __builtin_amdgcn_s_barrier();   // protect Vb (and cur bufs) for next DMA
        __builtin_amdgcn_sched_barrier(0);
    };

    #pragma unroll 1
    for (int tp = 0; tp < 16; ++tp) {    // unroll-by-2: cur constant per site
        tile_body(tp * 2, 0);
        tile_body(tp * 2 + 1, 1);
    }

    // epilogue: lane owns row q = W+lan16; reduce lsum over the 4 lane-groups
    float s = lsum;
    s += __shfl_xor(s, 16, 64);
    s += __shfl_xor(s, 32, 64);
    float inv = 1.f / s;
    const int row = i0 + W + lan16;
    #pragma unroll
    for (int nf = 0; nf < 4; ++nf)
        #pragma unroll
        for (int rg = 0; rg < 4; ++rg)
            out[(size_t)row * DM + col0 + nf * 16 + lgrp * 4 + rg] = accO[nf][rg] * inv;
}

// ---------------------------------------------------------------------------
extern "C" void kernel_launch(void* const* d_in, const int* in_sizes, int n_in,
                              void* d_out, int out_size, void* d_ws, size_t ws_size,
                              hipStream_t stream) {
    const float* w  = (const float*)d_in[0];
    const float* Wq = (const float*)d_in[1];
    const float* Wk = (const float*)d_in[2];
    const float* Wv = (const float*)d_in[3];
    const float* Wr = (const float*)d_in[4];
    const float* ub = (const float*)d_in[5];
    const float* vb = (const float*)d_in[6];
    float* out = (float*)d_out;

    const size_t U = 1048576;  // 1M shorts = 2MB
    unsigned short* ws = (unsigned short*)d_ws;
    unsigned short* wbf = ws;            // 2U
    unsigned short* Wqb = ws + 2 * U;
    unsigned short* Wkb = ws + 3 * U;
    unsigned short* Wvb = ws + 4 * U;
    unsigned short* Wrb = ws + 5 * U;
    unsigned short* qb  = ws + 6 * U;    // 2U
    unsigned short* kkb = ws + 8 * U;    // 2U
    unsigned short* vtg = ws + 10 * U;   // 2U (transposed V, [DM][LQ])
    // guarded rp: 128 zero rows + LR rows + 128 zero rows
    unsigned short* rpg = ws + 12 * U + 131072;                 // interior
    unsigned short* r   = rpg + (size_t)LR * DM + 131072;       // sinusoid (4U)

    dim3 blk(256);
    hipLaunchKernelGGL(prep, dim3(11390), blk, 0, stream, w, Wq, Wk, Wv, Wr, wbf, r, rpg);
    hipLaunchKernelGGL(proj_all, dim3(640), blk, 0, stream,
                       wbf, r, Wqb, Wkb, Wvb, Wrb, qb, kkb, vtg, rpg);
    hipLaunchKernelGGL(attn_mfma, dim3(512), blk, 0, stream,
                       qb, kkb, vtg, rpg, ub, vb, out);
}

// Round 14
// 132.426 us; speedup vs baseline: 1.0379x; 1.0379x over previous
//
#include <hip/hip_runtime.h>
#include <math.h>
#include <stddef.h>

#define LQ 2048
#define DM 1024
#define NH 16
#define DH 64
#define LR 4095  // 2*LQ-1

typedef __attribute__((ext_vector_type(4))) float f4v;
typedef __attribute__((ext_vector_type(8))) short s8v;
typedef __attribute__((ext_vector_type(2))) unsigned short us2;
typedef __attribute__((ext_vector_type(8))) unsigned short us8;
typedef __attribute__((ext_vector_type(2))) unsigned int u32x2;
typedef __attribute__((ext_vector_type(4))) unsigned int u32x4;

__device__ __forceinline__ unsigned short f2bf(float x) {
    unsigned int u = __float_as_uint(x);
    return (unsigned short)((u + 0x7FFFu + ((u >> 16) & 1u)) >> 16);
}
__device__ __forceinline__ float bf2f(unsigned short s) {
    return __uint_as_float(((unsigned int)s) << 16);
}
__device__ __forceinline__ unsigned cvtpk(float lo, float hi) {
    unsigned r;
    asm("v_cvt_pk_bf16_f32 %0, %1, %2" : "=v"(r) : "v"(lo), "v"(hi));
    return r;
}
template<int CTRL>
__device__ __forceinline__ float rot16(float x) {
    return __uint_as_float((unsigned)__builtin_amdgcn_update_dpp(
        0, (int)__float_as_uint(x), CTRL, 0xF, 0xF, false));
}
#define GLOAD16(g, l) __builtin_amdgcn_global_load_lds((g), (l), 16, 0, 0)
// fence for cross-lane LDS handoff within a wave (load-bearing! r5 NaN)
#define WAVE_LDS_FENCE() do { \
    asm volatile("s_waitcnt lgkmcnt(0)" ::: "memory"); \
    __builtin_amdgcn_sched_barrier(0); } while (0)

#define MFMA16(a, b, c) __builtin_amdgcn_mfma_f32_16x16x32_bf16((a), (b), (c), 0, 0, 0)

// swizzled read from linear-DMA-staged tile: byte ^= (row&7)<<4 (source was
// pre-swizzled col c8^(row&7), so this recovers global[row][colshort/8])
__device__ __forceinline__ s8v sw_read8(const unsigned short* base, int row, int colshort) {
    int byte = (row * 128 + colshort * 2) ^ ((row & 7) << 4);
    return *(const s8v*)((const char*)base + byte);
}

// ---------------------------------------------------------------------------
// prep: [0,3072) cast f32->bf16 [w|Wq|Wk|Wv|Wr]; [3072,11262) sinusoid r;
// [11262,11390) zero the 128-row guards around rp.
// ---------------------------------------------------------------------------
__global__ __launch_bounds__(256)
void prep(const float* __restrict__ w, const float* __restrict__ Wq,
          const float* __restrict__ Wk, const float* __restrict__ Wv,
          const float* __restrict__ Wr, unsigned short* __restrict__ dst,
          unsigned short* __restrict__ r, unsigned short* __restrict__ rpg) {
    int b = blockIdx.x;
    if (b < 3072) {
        size_t e0 = ((size_t)b * 256 + threadIdx.x) * 8;
        const float* src;
        if (e0 < (size_t)LQ * DM) src = w + e0;
        else {
            size_t ro = e0 - (size_t)LQ * DM;
            int wi = (int)(ro >> 20);
            size_t off = ro & 1048575;
            src = (wi == 0 ? Wq : wi == 1 ? Wk : wi == 2 ? Wv : Wr) + off;
        }
        f4v a = *(const f4v*)src;
        f4v c = *(const f4v*)(src + 4);
        us8 o;
        o[0]=f2bf(a[0]); o[1]=f2bf(a[1]); o[2]=f2bf(a[2]); o[3]=f2bf(a[3]);
        o[4]=f2bf(c[0]); o[5]=f2bf(c[1]); o[6]=f2bf(c[2]); o[7]=f2bf(c[3]);
        *(us8*)(dst + e0) = o;
    } else if (b < 11262) {
        int tg = (b - 3072) * 256 + threadIdx.x;   // LR*512 exactly
        int gm = tg >> 9, c2 = tg & 511;
        float invf = expf(-(float)c2 * (9.210340371976184f / 512.0f));
        float ang = (float)(gm - (LQ - 1)) * invf;
        float sv, cv;
        sincosf(ang, &sv, &cv);
        us2 o; o[0] = f2bf(sv); o[1] = f2bf(cv);
        *(us2*)&r[(size_t)gm * DM + c2 * 2] = o;
    } else {
        int idx = (b - 11262) * 2048 + threadIdx.x * 8;  // [0, 262144)
        unsigned short* p = (idx < 131072)
            ? (rpg - 131072 + idx)
            : (rpg + (size_t)LR * DM + (idx - 131072));
        *(us8*)p = (us8){0,0,0,0,0,0,0,0};
    }
}

// ---------------------------------------------------------------------------
// All 4 projections, 128x128 tile (m97 geometry), BK=64, global_load_lds(16),
// linear LDS, 4 waves each owning a 64x64 quadrant (4x4 frags).
// XCD-aware swizzle (640%8==0 -> bijective): consecutive logical blocks share
// the A-panel and land on the same XCD's L2.
// logical [0,384): QKV (mat = l>>7); [384,640): rp (mat=3).
// mat==2 writes C transposed (vt[n][m]) via an LDS-transpose epilogue.
// ---------------------------------------------------------------------------
__global__ __launch_bounds__(256)
void proj_all(const unsigned short* __restrict__ wbf, const unsigned short* __restrict__ rr,
              const unsigned short* __restrict__ Wqb, const unsigned short* __restrict__ Wkb,
              const unsigned short* __restrict__ Wvb, const unsigned short* __restrict__ Wrb,
              unsigned short* __restrict__ qb, unsigned short* __restrict__ kkb,
              unsigned short* __restrict__ vtg, unsigned short* __restrict__ rpg) {
    __shared__ unsigned short ldsbuf[2 * 128 * 64];
    unsigned short* As = ldsbuf;
    unsigned short* Bs = ldsbuf + 128 * 64;
    int bid = (blockIdx.x & 7) * 80 + (blockIdx.x >> 3);   // XCD swizzle, 640=8x80
    int mat, mblk, nblk;
    if (bid < 384) { mat = bid >> 7; int rm = bid & 127; mblk = rm >> 3; nblk = rm & 7; }
    else           { mat = 3; int rm = bid - 384; mblk = rm >> 3; nblk = rm & 7; }
    const int M = (mat < 3) ? LQ : LR;
    const unsigned short* A = (mat < 3) ? wbf : rr;
    const unsigned short* B = mat == 0 ? Wqb : mat == 1 ? Wkb : mat == 2 ? Wvb : Wrb;
    unsigned short* C = mat == 0 ? qb : mat == 1 ? kkb : mat == 2 ? vtg : rpg;
    const int m0 = mblk * 128, n0 = nblk * 128;
    const int t = threadIdx.x;
    const int w = t >> 6, lan16 = t & 15, lgrp = (t & 63) >> 4;
    const int wm = (w >> 1) * 64, wn = (w & 1) * 64;
    f4v acc[4][4] = {};

    for (int k0 = 0; k0 < DM; k0 += 64) {
        #pragma unroll
        for (int it = 0; it < 4; ++it) {
            int slot = it * 256 + t;
            int row = slot >> 3, c8 = slot & 7;
            int gm = m0 + row; if (gm > M - 1) gm = M - 1;
            GLOAD16(A + (size_t)gm * DM + k0 + c8 * 8,
                    (char*)As + (size_t)(it * 256 + (t & ~63)) * 16);
            GLOAD16(B + (size_t)(n0 + row) * DM + k0 + c8 * 8,
                    (char*)Bs + (size_t)(it * 256 + (t & ~63)) * 16);
        }
        __syncthreads();
        #pragma unroll
        for (int kk = 0; kk < 2; ++kk) {
            s8v aF[4], bF[4];
            #pragma unroll
            for (int i = 0; i < 4; ++i) {
                aF[i] = *(const s8v*)&As[(wm + i * 16 + lan16) * 64 + kk * 32 + lgrp * 8];
                bF[i] = *(const s8v*)&Bs[(wn + i * 16 + lan16) * 64 + kk * 32 + lgrp * 8];
            }
            #pragma unroll
            for (int i = 0; i < 4; ++i)
                #pragma unroll
                for (int j = 0; j < 4; ++j)
                    acc[i][j] = MFMA16(aF[i], bF[j], acc[i][j]);
        }
        __syncthreads();
    }
    if (mat != 2) {
        #pragma unroll
        for (int i = 0; i < 4; ++i)
            #pragma unroll
            for (int j = 0; j < 4; ++j)
                #pragma unroll
                for (int rg = 0; rg < 4; ++rg) {
                    int row = m0 + wm + i * 16 + lgrp * 4 + rg;
                    if (row < M)
                        C[(size_t)row * DM + n0 + wn + j * 16 + lan16] = f2bf(acc[i][j][rg]);
                }
    } else {
        // stage C^T in LDS ([128 n][128 m] bf16, byte ^= (n&7)<<4), then
        // coalesced us8 row stores to vt[n][m].
        unsigned short* Ct = ldsbuf;   // reuses As+Bs (dead after last barrier)
        #pragma unroll
        for (int i = 0; i < 4; ++i)
            #pragma unroll
            for (int j = 0; j < 4; ++j) {
                int n = wn + j * 16 + lan16;
                int mb = wm + i * 16 + lgrp * 4;
                int byte = (n * 256 + mb * 2) ^ ((n & 7) << 4);
                u32x2 pp;
                pp[0] = cvtpk(acc[i][j][0], acc[i][j][1]);
                pp[1] = cvtpk(acc[i][j][2], acc[i][j][3]);
                *(u32x2*)((char*)Ct + byte) = pp;
            }
        __syncthreads();
        #pragma unroll
        for (int it = 0; it < 8; ++it) {
            int slot = it * 256 + t;
            int n = slot >> 4, c8 = slot & 15;
            int byte = (n * 256 + c8 * 16) ^ ((n & 7) << 4);
            us8 v = *(const us8*)((const char*)Ct + byte);
            *(us8*)&C[(size_t)(n0 + n) * LQ + m0 + c8 * 8] = v;
        }
    }
}

// ---------------------------------------------------------------------------
// Fused rel-attention (r12 pipeline, verified 80.3us). Block = (head, 64 q
// rows), full j-range (32 tiles). K+band double-buffered via global_load_lds
// with pre-swizzled source, prefetched a full tile ahead; V single-buffered;
// counted vmcnt(8)/vmcnt(6) + 3 raw barriers/tile (never drain to 0).
// Unroll-by-2 makes buffer index compile-time; setprio around MFMA clusters.
// Fixed-max softmax; rel-shift masks via zero guard rows around rp.
// ---------------------------------------------------------------------------
__global__ __launch_bounds__(256, 2)
void attn_mfma(const unsigned short* __restrict__ q, const unsigned short* __restrict__ kkg,
               const unsigned short* __restrict__ vtg, const unsigned short* __restrict__ rpg,
               const float* __restrict__ ub, const float* __restrict__ vb,
               float* __restrict__ out) {
    __shared__ unsigned short Kb[2][64 * 64];
    __shared__ unsigned short Bb[2][128 * 64];
    __shared__ unsigned short Vb[64 * 64];
    __shared__ unsigned short Gtw[4][80 * 20];
    __shared__ unsigned short Pt[4][64 * 18];

    // XCD swizzle: 512 = 8 x 64 (2 heads per XCD chunk)
    const int dd = blockIdx.x;
    const int f = (dd & 7) * 64 + (dd >> 3);
    const int h = f >> 5;
    const int i0 = (f & 31) * 64;
    const int col0 = h * DH;

    const int t = threadIdx.x;
    const int w = t >> 6, lan16 = t & 15, lgrp = (t & 63) >> 4;
    const int W = w * 16;
    const int cbase = 48 - W;
    const float C1 = 0.125f * 1.4426950408889634f;
    const float C0 = -4.0f * 1.4426950408889634f;

    unsigned short* gw = Gtw[w];
    unsigned short* pw = Pt[w];

    // Q fragments direct from global + f32 bias
    union uv { u32x4 u; s8v s; };
    auto mkfrag = [&](int gi, const float* bias, s8v* dstf) {
        #pragma unroll
        for (int kk = 0; kk < 2; ++kk) {
            int cb = kk * 32 + lgrp * 8;
            us8 qv = (us8){0,0,0,0,0,0,0,0};
            if (gi < LQ) qv = *(const us8*)(q + (size_t)gi * DM + col0 + cb);
            f4v b0 = *(const f4v*)(bias + col0 + cb);
            f4v b1 = *(const f4v*)(bias + col0 + cb + 4);
            uv o;
            o.u[0] = cvtpk(bf2f(qv[0]) + b0[0], bf2f(qv[1]) + b0[1]);
            o.u[1] = cvtpk(bf2f(qv[2]) + b0[2], bf2f(qv[3]) + b0[3]);
            o.u[2] = cvtpk(bf2f(qv[4]) + b1[0], bf2f(qv[5]) + b1[1]);
            o.u[3] = cvtpk(bf2f(qv[6]) + b1[2], bf2f(qv[7]) + b1[3]);
            dstf[kk] = o.s;
        }
    };
    s8v quF[2], qvlF[2], qvsF[2];
    mkfrag(i0 + W + lan16, ub, quF);
    mkfrag(i0 + W + lan16, vb, qvlF);
    mkfrag(i0 + W + 1 + lan16, vb, qvsF);

    // DMA staging: linear LDS dest (wave base + lane*16), pre-swizzled source
    auto stageK = [&](int j0, int buf) {
        #pragma unroll
        for (int it = 0; it < 2; ++it) {
            int slot = it * 256 + t;
            int row = slot >> 3, c8 = (t & 7) ^ (row & 7);
            GLOAD16(kkg + (size_t)(j0 + row) * DM + col0 + c8 * 8,
                    (char*)&Kb[buf][0] + (size_t)(it * 256 + (t & ~63)) * 16);
        }
    };
    auto stageB = [&](int rel, int buf) {
        int base = (rel <= 0) ? rel + 4031 : rel - 65;
        #pragma unroll
        for (int it = 0; it < 4; ++it) {
            int slot = it * 256 + t;
            int row = slot >> 3, c8 = (t & 7) ^ (row & 7);
            GLOAD16(rpg + (ptrdiff_t)(base + row) * DM + col0 + c8 * 8,
                    (char*)&Bb[buf][0] + (size_t)(it * 256 + (t & ~63)) * 16);
        }
    };
    auto stageV = [&](int j0) {
        #pragma unroll
        for (int it = 0; it < 2; ++it) {
            int slot = it * 256 + t;
            int row = slot >> 3, c8 = (t & 7) ^ (row & 7);
            GLOAD16(vtg + (size_t)(col0 + row) * LQ + j0 + c8 * 8,
                    (char*)&Vb[0] + (size_t)(it * 256 + (t & ~63)) * 16);
        }
    };

    f4v accO[4] = {};
    float lsum[4] = {0.f, 0.f, 0.f, 0.f};

    stageK(0, 0);
    stageB(0 - i0, 0);

    // one j-tile; cur is a compile-time constant at each call site
    auto tile_body = [&](int tt, int cur) {
        const int j0 = tt * 64;
        const int rel = j0 - i0;
        stageV(j0);                                // 2 VMEM
        const int tn = (tt < 31) ? tt + 1 : 31;
        stageK(tn * 64, cur ^ 1);                  // 2 VMEM
        stageB(tn * 64 - i0, cur ^ 1);             // 4 VMEM
        __builtin_amdgcn_sched_barrier(0);
        asm volatile("s_waitcnt vmcnt(8)" ::: "memory");  // K/B of tile t done
        __builtin_amdgcn_s_barrier();
        __builtin_amdgcn_sched_barrier(0);

        // AC = QU @ K^T
        __builtin_amdgcn_s_setprio(1);
        f4v acF[4] = {};
        #pragma unroll
        for (int nf = 0; nf < 4; ++nf)
            #pragma unroll
            for (int kk = 0; kk < 2; ++kk) {
                s8v bF = sw_read8(&Kb[cur][0], nf * 16 + lan16, kk * 32 + lgrp * 8);
                acF[nf] = MFMA16(quF[kk], bF, acF[nf]);
            }
        // BD: G = QV @ band^T (staged band; guards encode the region mask)
        f4v g[5] = {};
        {
            const s8v* qf = (rel <= 0) ? qvlF : qvsF;
            #pragma unroll
            for (int c = 0; c < 5; ++c)
                #pragma unroll
                for (int kk = 0; kk < 2; ++kk) {
                    s8v bF = sw_read8(&Bb[cur][0], cbase + c * 16 + lan16, kk * 32 + lgrp * 8);
                    g[c] = MFMA16(qf[kk], bF, g[c]);
                }
        }
        __builtin_amdgcn_s_setprio(0);
        if (rel == 0) {   // diag tile: upper band direct from global (once/block)
            #pragma unroll
            for (int c = 0; c < 5; ++c) {
                int trow = -65 + cbase + c * 16 + lan16;
                const unsigned short* bp = rpg + (ptrdiff_t)trow * DM + col0;
                #pragma unroll
                for (int kk = 0; kk < 2; ++kk) {
                    us8 bv = *(const us8*)(bp + kk * 32 + lgrp * 8);
                    g[c] = MFMA16(qvsF[kk], (s8v)bv, g[c]);
                }
            }
        }
        // sheared G store, b64-packed (pitch 20)
        #pragma unroll
        for (int c = 0; c < 5; ++c) {
            int cl = c * 16 + lan16;
            u32x2 pp;
            pp[0] = cvtpk(g[c][0], g[c][1]);
            pp[1] = cvtpk(g[c][2], g[c][3]);
            *(u32x2*)&gw[cl * 20 + lgrp * 4] = pp;
        }
        WAVE_LDS_FENCE();   // G stores -> softmax reads

        // fixed-max softmax; P -> P^T[jl][rhat] (pitch 18)
        #pragma unroll
        for (int nf = 0; nf < 4; ++nf) {
            int jl = nf * 16 + lan16;
            float pp[4];
            #pragma unroll
            for (int rg = 0; rg < 4; ++rg) {
                const int rhat = lgrp * 4 + rg;
                float bd = bf2f(gw[(jl - rhat + 15) * 20 + rhat]);
                pp[rg] = exp2f(fmaf(acF[nf][rg] + bd, C1, C0));
                lsum[rg] += pp[rg];
            }
            *(unsigned*)&pw[jl * 18 + lgrp * 4]     = cvtpk(pp[0], pp[1]);
            *(unsigned*)&pw[jl * 18 + lgrp * 4 + 2] = cvtpk(pp[2], pp[3]);
        }
        WAVE_LDS_FENCE();   // P stores -> pF gather

        s8v pF[2];
        #pragma unroll
        for (int kk = 0; kk < 2; ++kk) {
            us8 tmp;
            #pragma unroll
            for (int e = 0; e < 8; ++e)
                tmp[e] = pw[(kk * 32 + lgrp * 8 + e) * 18 + lan16];
            pF[kk] = (s8v)tmp;
        }
        __builtin_amdgcn_sched_barrier(0);
        asm volatile("s_waitcnt vmcnt(6)" ::: "memory");  // V of tile t done
        __builtin_amdgcn_s_barrier();
        __builtin_amdgcn_sched_barrier(0);

        // PV
        __builtin_amdgcn_s_setprio(1);
        #pragma unroll
        for (int nf = 0; nf < 4; ++nf)
            #pragma unroll
            for (int kk = 0; kk < 2; ++kk) {
                s8v vF = sw_read8(&Vb[0], nf * 16 + lan16, kk * 32 + lgrp * 8);
                accO[nf] = MFMA16(pF[kk], vF, accO[nf]);
            }
        __builtin_amdgcn_s_setprio(0);
        __builtin_amdgcn_sched_barrier(0);
        __builtin_amdgcn_s_barrier();   // protect Vb (and cur bufs) for next DMA
        __builtin_amdgcn_sched_barrier(0);
    };

    #pragma unroll 1
    for (int tp = 0; tp < 16; ++tp) {    // unroll-by-2: cur constant per site
        tile_body(tp * 2, 0);
        tile_body(tp * 2 + 1, 1);
    }

    // epilogue: full row-sum (DPP over lan16), normalize, store
    #pragma unroll
    for (int rg = 0; rg < 4; ++rg) {
        float s = lsum[rg];
        s += rot16<0x121>(s);
        s += rot16<0x122>(s);
        s += rot16<0x124>(s);
        s += rot16<0x128>(s);
        float inv = 1.f / s;
        const int row = i0 + W + lgrp * 4 + rg;
        #pragma unroll
        for (int nf = 0; nf < 4; ++nf)
            out[(size_t)row * DM + col0 + nf * 16 + lan16] = accO[nf][rg] * inv;
    }
}

// ---------------------------------------------------------------------------
extern "C" void kernel_launch(void* const* d_in, const int* in_sizes, int n_in,
                              void* d_out, int out_size, void* d_ws, size_t ws_size,
                              hipStream_t stream) {
    const float* w  = (const float*)d_in[0];
    const float* Wq = (const float*)d_in[1];
    const float* Wk = (const float*)d_in[2];
    const float* Wv = (const float*)d_in[3];
    const float* Wr = (const float*)d_in[4];
    const float* ub = (const float*)d_in[5];
    const float* vb = (const float*)d_in[6];
    float* out = (float*)d_out;

    const size_t U = 1048576;  // 1M shorts = 2MB
    unsigned short* ws = (unsigned short*)d_ws;
    unsigned short* wbf = ws;            // 2U
    unsigned short* Wqb = ws + 2 * U;
    unsigned short* Wkb = ws + 3 * U;
    unsigned short* Wvb = ws + 4 * U;
    unsigned short* Wrb = ws + 5 * U;
    unsigned short* qb  = ws + 6 * U;    // 2U
    unsigned short* kkb = ws + 8 * U;    // 2U
    unsigned short* vtg = ws + 10 * U;   // 2U (transposed V, [DM][LQ])
    // guarded rp: 128 zero rows + LR rows + 128 zero rows
    unsigned short* rpg = ws + 12 * U + 131072;                 // interior
    unsigned short* r   = rpg + (size_t)LR * DM + 131072;       // sinusoid (4U)

    dim3 blk(256);
    hipLaunchKernelGGL(prep, dim3(11390), blk, 0, stream, w, Wq, Wk, Wv, Wr, wbf, r, rpg);
    hipLaunchKernelGGL(proj_all, dim3(640), blk, 0, stream,
                       wbf, r, Wqb, Wkb, Wvb, Wrb, qb, kkb, vtg, rpg);
    hipLaunchKernelGGL(attn_mfma, dim3(512), blk, 0, stream,
                       qb, kkb, vtg, rpg, ub, vb, out);
}

// Round 15
// 131.104 us; speedup vs baseline: 1.0483x; 1.0101x over previous
//
#include <hip/hip_runtime.h>
#include <math.h>
#include <stddef.h>

#define LQ 2048
#define DM 1024
#define NH 16
#define DH 64
#define LR 4095  // 2*LQ-1

typedef __attribute__((ext_vector_type(4))) float f4v;
typedef __attribute__((ext_vector_type(8))) short s8v;
typedef __attribute__((ext_vector_type(2))) unsigned short us2;
typedef __attribute__((ext_vector_type(8))) unsigned short us8;
typedef __attribute__((ext_vector_type(2))) unsigned int u32x2;
typedef __attribute__((ext_vector_type(4))) unsigned int u32x4;

__device__ __forceinline__ unsigned short f2bf(float x) {
    unsigned int u = __float_as_uint(x);
    return (unsigned short)((u + 0x7FFFu + ((u >> 16) & 1u)) >> 16);
}
__device__ __forceinline__ float bf2f(unsigned short s) {
    return __uint_as_float(((unsigned int)s) << 16);
}
__device__ __forceinline__ unsigned cvtpk(float lo, float hi) {
    unsigned r;
    asm("v_cvt_pk_bf16_f32 %0, %1, %2" : "=v"(r) : "v"(lo), "v"(hi));
    return r;
}
template<int CTRL>
__device__ __forceinline__ float rot16(float x) {
    return __uint_as_float((unsigned)__builtin_amdgcn_update_dpp(
        0, (int)__float_as_uint(x), CTRL, 0xF, 0xF, false));
}
#define GLOAD16(g, l) __builtin_amdgcn_global_load_lds((g), (l), 16, 0, 0)
// fence for cross-lane LDS handoff within a wave (load-bearing! r5 NaN)
#define WAVE_LDS_FENCE() do { \
    asm volatile("s_waitcnt lgkmcnt(0)" ::: "memory"); \
    __builtin_amdgcn_sched_barrier(0); } while (0)

#define MFMA16(a, b, c) __builtin_amdgcn_mfma_f32_16x16x32_bf16((a), (b), (c), 0, 0, 0)

// swizzled read from linear-DMA-staged tile: byte ^= (row&7)<<4 (source was
// pre-swizzled col c8^(row&7), so this recovers global[row][colshort/8])
__device__ __forceinline__ s8v sw_read8(const unsigned short* base, int row, int colshort) {
    int byte = (row * 128 + colshort * 2) ^ ((row & 7) << 4);
    return *(const s8v*)((const char*)base + byte);
}

// ---------------------------------------------------------------------------
// prep: [0,3072) cast f32->bf16 [w|Wq|Wk|Wv|Wr]; [3072,11262) sinusoid r;
// [11262,11390) zero the 128-row guards around rp.
// ---------------------------------------------------------------------------
__global__ __launch_bounds__(256)
void prep(const float* __restrict__ w, const float* __restrict__ Wq,
          const float* __restrict__ Wk, const float* __restrict__ Wv,
          const float* __restrict__ Wr, unsigned short* __restrict__ dst,
          unsigned short* __restrict__ r, unsigned short* __restrict__ rpg) {
    int b = blockIdx.x;
    if (b < 3072) {
        size_t e0 = ((size_t)b * 256 + threadIdx.x) * 8;
        const float* src;
        if (e0 < (size_t)LQ * DM) src = w + e0;
        else {
            size_t ro = e0 - (size_t)LQ * DM;
            int wi = (int)(ro >> 20);
            size_t off = ro & 1048575;
            src = (wi == 0 ? Wq : wi == 1 ? Wk : wi == 2 ? Wv : Wr) + off;
        }
        f4v a = *(const f4v*)src;
        f4v c = *(const f4v*)(src + 4);
        us8 o;
        o[0]=f2bf(a[0]); o[1]=f2bf(a[1]); o[2]=f2bf(a[2]); o[3]=f2bf(a[3]);
        o[4]=f2bf(c[0]); o[5]=f2bf(c[1]); o[6]=f2bf(c[2]); o[7]=f2bf(c[3]);
        *(us8*)(dst + e0) = o;
    } else if (b < 11262) {
        int tg = (b - 3072) * 256 + threadIdx.x;   // LR*512 exactly
        int gm = tg >> 9, c2 = tg & 511;
        float invf = expf(-(float)c2 * (9.210340371976184f / 512.0f));
        float ang = (float)(gm - (LQ - 1)) * invf;
        float sv, cv;
        sincosf(ang, &sv, &cv);
        us2 o; o[0] = f2bf(sv); o[1] = f2bf(cv);
        *(us2*)&r[(size_t)gm * DM + c2 * 2] = o;
    } else {
        int idx = (b - 11262) * 2048 + threadIdx.x * 8;  // [0, 262144)
        unsigned short* p = (idx < 131072)
            ? (rpg - 131072 + idx)
            : (rpg + (size_t)LR * DM + (idx - 131072));
        *(us8*)p = (us8){0,0,0,0,0,0,0,0};
    }
}

// ---------------------------------------------------------------------------
// All 4 projections, 128x128 tile (m97 geometry), BK=64, global_load_lds(16),
// linear LDS, 4 waves each owning a 64x64 quadrant (4x4 frags).
// blocks [0,384): QKV (mat = bid>>7); [384,640): rp (mat=3).
// mat==2 writes C transposed (vt[n][m]) via an LDS-transpose epilogue so the
// global stores are coalesced us8 rows.
// ---------------------------------------------------------------------------
__global__ __launch_bounds__(256)
void proj_all(const unsigned short* __restrict__ wbf, const unsigned short* __restrict__ rr,
              const unsigned short* __restrict__ Wqb, const unsigned short* __restrict__ Wkb,
              const unsigned short* __restrict__ Wvb, const unsigned short* __restrict__ Wrb,
              unsigned short* __restrict__ qb, unsigned short* __restrict__ kkb,
              unsigned short* __restrict__ vtg, unsigned short* __restrict__ rpg) {
    __shared__ unsigned short ldsbuf[2 * 128 * 64];
    unsigned short* As = ldsbuf;
    unsigned short* Bs = ldsbuf + 128 * 64;
    int bid = blockIdx.x;
    int mat, mblk, nblk;
    if (bid < 384) { mat = bid >> 7; int rm = bid & 127; mblk = rm >> 3; nblk = rm & 7; }
    else           { mat = 3; int rm = bid - 384; mblk = rm >> 3; nblk = rm & 7; }
    const int M = (mat < 3) ? LQ : LR;
    const unsigned short* A = (mat < 3) ? wbf : rr;
    const unsigned short* B = mat == 0 ? Wqb : mat == 1 ? Wkb : mat == 2 ? Wvb : Wrb;
    unsigned short* C = mat == 0 ? qb : mat == 1 ? kkb : mat == 2 ? vtg : rpg;
    const int m0 = mblk * 128, n0 = nblk * 128;
    const int t = threadIdx.x;
    const int w = t >> 6, lan16 = t & 15, lgrp = (t & 63) >> 4;
    const int wm = (w >> 1) * 64, wn = (w & 1) * 64;
    f4v acc[4][4] = {};

    for (int k0 = 0; k0 < DM; k0 += 64) {
        #pragma unroll
        for (int it = 0; it < 4; ++it) {
            int slot = it * 256 + t;
            int row = slot >> 3, c8 = slot & 7;
            int gm = m0 + row; if (gm > M - 1) gm = M - 1;
            GLOAD16(A + (size_t)gm * DM + k0 + c8 * 8,
                    (char*)As + (size_t)(it * 256 + (t & ~63)) * 16);
            GLOAD16(B + (size_t)(n0 + row) * DM + k0 + c8 * 8,
                    (char*)Bs + (size_t)(it * 256 + (t & ~63)) * 16);
        }
        __syncthreads();
        #pragma unroll
        for (int kk = 0; kk < 2; ++kk) {
            s8v aF[4], bF[4];
            #pragma unroll
            for (int i = 0; i < 4; ++i) {
                aF[i] = *(const s8v*)&As[(wm + i * 16 + lan16) * 64 + kk * 32 + lgrp * 8];
                bF[i] = *(const s8v*)&Bs[(wn + i * 16 + lan16) * 64 + kk * 32 + lgrp * 8];
            }
            #pragma unroll
            for (int i = 0; i < 4; ++i)
                #pragma unroll
                for (int j = 0; j < 4; ++j)
                    acc[i][j] = MFMA16(aF[i], bF[j], acc[i][j]);
        }
        __syncthreads();
    }
    if (mat != 2) {
        #pragma unroll
        for (int i = 0; i < 4; ++i)
            #pragma unroll
            for (int j = 0; j < 4; ++j)
                #pragma unroll
                for (int rg = 0; rg < 4; ++rg) {
                    int row = m0 + wm + i * 16 + lgrp * 4 + rg;
                    if (row < M)
                        C[(size_t)row * DM + n0 + wn + j * 16 + lan16] = f2bf(acc[i][j][rg]);
                }
    } else {
        // stage C^T in LDS ([128 n][128 m] bf16, byte ^= (n&7)<<4), then
        // coalesced us8 row stores to vt[n][m].
        unsigned short* Ct = ldsbuf;   // reuses As+Bs (dead after last barrier)
        #pragma unroll
        for (int i = 0; i < 4; ++i)
            #pragma unroll
            for (int j = 0; j < 4; ++j) {
                int n = wn + j * 16 + lan16;
                int mb = wm + i * 16 + lgrp * 4;
                int byte = (n * 256 + mb * 2) ^ ((n & 7) << 4);
                u32x2 pp;
                pp[0] = cvtpk(acc[i][j][0], acc[i][j][1]);
                pp[1] = cvtpk(acc[i][j][2], acc[i][j][3]);
                *(u32x2*)((char*)Ct + byte) = pp;
            }
        __syncthreads();
        #pragma unroll
        for (int it = 0; it < 8; ++it) {
            int slot = it * 256 + t;
            int n = slot >> 4, c8 = slot & 15;
            int byte = (n * 256 + c8 * 16) ^ ((n & 7) << 4);
            us8 v = *(const us8*)((const char*)Ct + byte);
            *(us8*)&C[(size_t)(n0 + n) * LQ + m0 + c8 * 8] = v;
        }
    }
}

// ---------------------------------------------------------------------------
// Fused rel-attention with DEFERRED-PV cross-tile pipeline. Block = (head,
// 64 q rows), 32 j-tiles. Per tile: one counted vmcnt(8) + 2 barriers.
// PV(t-1) issues right after the top barrier using register-carried pFprev
// and double-buffered Vb (zero memory wait), then AC/BD(t) (Kb/Bb staged two
// tiles ahead). G and P^T share the wave-private GP region (read-all-G-first
// fold). Fixed-max softmax; rel-shift masks via zero guard rows around rp.
// Prologue stages a dummy V so PV(-1) is 0 x finite (NaN-safe).
// ---------------------------------------------------------------------------
__global__ __launch_bounds__(256, 2)
void attn_mfma(const unsigned short* __restrict__ q, const unsigned short* __restrict__ kkg,
               const unsigned short* __restrict__ vtg, const unsigned short* __restrict__ rpg,
               const float* __restrict__ ub, const float* __restrict__ vb,
               float* __restrict__ out) {
    __shared__ unsigned short Kb[2][64 * 64];     // 16 KB
    __shared__ unsigned short Bb[2][128 * 64];    // 32 KB
    __shared__ unsigned short Vb[2][64 * 64];     // 16 KB
    __shared__ unsigned short GP[4][80 * 20];     // 12.8 KB (G shear, then P^T)

    // XCD swizzle: 512 = 8 x 64 (2 heads per XCD chunk)
    const int dd = blockIdx.x;
    const int f = (dd & 7) * 64 + (dd >> 3);
    const int h = f >> 5;
    const int i0 = (f & 31) * 64;
    const int col0 = h * DH;

    const int t = threadIdx.x;
    const int w = t >> 6, lan16 = t & 15, lgrp = (t & 63) >> 4;
    const int W = w * 16;
    const int cbase = 48 - W;
    const float C1 = 0.125f * 1.4426950408889634f;
    const float C0 = -4.0f * 1.4426950408889634f;

    unsigned short* gw = GP[w];

    // Q fragments direct from global + f32 bias
    union uv { u32x4 u; s8v s; };
    auto mkfrag = [&](int gi, const float* bias, s8v* dstf) {
        #pragma unroll
        for (int kk = 0; kk < 2; ++kk) {
            int cb = kk * 32 + lgrp * 8;
            us8 qv = (us8){0,0,0,0,0,0,0,0};
            if (gi < LQ) qv = *(const us8*)(q + (size_t)gi * DM + col0 + cb);
            f4v b0 = *(const f4v*)(bias + col0 + cb);
            f4v b1 = *(const f4v*)(bias + col0 + cb + 4);
            uv o;
            o.u[0] = cvtpk(bf2f(qv[0]) + b0[0], bf2f(qv[1]) + b0[1]);
            o.u[1] = cvtpk(bf2f(qv[2]) + b0[2], bf2f(qv[3]) + b0[3]);
            o.u[2] = cvtpk(bf2f(qv[4]) + b1[0], bf2f(qv[5]) + b1[1]);
            o.u[3] = cvtpk(bf2f(qv[6]) + b1[2], bf2f(qv[7]) + b1[3]);
            dstf[kk] = o.s;
        }
    };
    s8v quF[2], qvlF[2], qvsF[2];
    mkfrag(i0 + W + lan16, ub, quF);
    mkfrag(i0 + W + lan16, vb, qvlF);
    mkfrag(i0 + W + 1 + lan16, vb, qvsF);

    // DMA staging: linear LDS dest (wave base + lane*16), pre-swizzled source
    auto stageK = [&](int j0, int buf) {        // 2 VMEM
        #pragma unroll
        for (int it = 0; it < 2; ++it) {
            int slot = it * 256 + t;
            int row = slot >> 3, c8 = (t & 7) ^ (row & 7);
            GLOAD16(kkg + (size_t)(j0 + row) * DM + col0 + c8 * 8,
                    (char*)&Kb[buf][0] + (size_t)(it * 256 + (t & ~63)) * 16);
        }
    };
    auto stageB = [&](int rel, int buf) {       // 4 VMEM
        int base = (rel <= 0) ? rel + 4031 : rel - 65;
        #pragma unroll
        for (int it = 0; it < 4; ++it) {
            int slot = it * 256 + t;
            int row = slot >> 3, c8 = (t & 7) ^ (row & 7);
            GLOAD16(rpg + (ptrdiff_t)(base + row) * DM + col0 + c8 * 8,
                    (char*)&Bb[buf][0] + (size_t)(it * 256 + (t & ~63)) * 16);
        }
    };
    auto stageV = [&](int j0, int buf) {        // 2 VMEM
        #pragma unroll
        for (int it = 0; it < 2; ++it) {
            int slot = it * 256 + t;
            int row = slot >> 3, c8 = (t & 7) ^ (row & 7);
            GLOAD16(vtg + (size_t)(col0 + row) * LQ + j0 + c8 * 8,
                    (char*)&Vb[buf][0] + (size_t)(it * 256 + (t & ~63)) * 16);
        }
    };

    f4v accO[4] = {};
    float lsum[4] = {0.f, 0.f, 0.f, 0.f};
    s8v pFprev[2] = {};   // zero: PV(-1) contributes 0 x (finite dummy V) = 0

    // prologue: K0,B0 | dummyV(buf1) | V0(buf0) | K1,B1  -> 16 VMEM
    stageK(0, 0);
    stageB(0 - i0, 0);
    stageV(0, 1);          // dummy, read by PV(-1) only (weights are zero)
    stageV(0, 0);
    stageK(64, 1);
    stageB(64 - i0, 1);

    // one j-tile; cur = tt&1 is a compile-time constant at each call site
    auto tile_body = [&](int tt, int cur) {
        const int j0 = tt * 64;
        const int rel = j0 - i0;
        __builtin_amdgcn_sched_barrier(0);
        // oldest 8 = {V(t-1...),K(t),B(t)} batch -> staged & landed
        asm volatile("s_waitcnt vmcnt(8)" ::: "memory");
        __builtin_amdgcn_s_barrier();            // B1
        __builtin_amdgcn_sched_barrier(0);

        __builtin_amdgcn_s_setprio(1);
        // PV(t-1): zero memory wait (pFprev in regs, Vb[cur^1] staged long ago)
        #pragma unroll
        for (int nf = 0; nf < 4; ++nf)
            #pragma unroll
            for (int kk = 0; kk < 2; ++kk) {
                s8v vF = sw_read8(&Vb[cur ^ 1][0], nf * 16 + lan16, kk * 32 + lgrp * 8);
                accO[nf] = MFMA16(pFprev[kk], vF, accO[nf]);
            }
        // AC = QU @ K^T
        f4v acF[4] = {};
        #pragma unroll
        for (int nf = 0; nf < 4; ++nf)
            #pragma unroll
            for (int kk = 0; kk < 2; ++kk) {
                s8v bF = sw_read8(&Kb[cur][0], nf * 16 + lan16, kk * 32 + lgrp * 8);
                acF[nf] = MFMA16(quF[kk], bF, acF[nf]);
            }
        // BD: G = QV @ band^T (staged band; guards encode the region mask)
        f4v g[5] = {};
        {
            const s8v* qf = (rel <= 0) ? qvlF : qvsF;
            #pragma unroll
            for (int c = 0; c < 5; ++c)
                #pragma unroll
                for (int kk = 0; kk < 2; ++kk) {
                    s8v bF = sw_read8(&Bb[cur][0], cbase + c * 16 + lan16, kk * 32 + lgrp * 8);
                    g[c] = MFMA16(qf[kk], bF, g[c]);
                }
        }
        __builtin_amdgcn_s_setprio(0);
        if (rel == 0) {   // diag tile: upper band direct from global (once/block)
            #pragma unroll
            for (int c = 0; c < 5; ++c) {
                int trow = -65 + cbase + c * 16 + lan16;
                const unsigned short* bp = rpg + (ptrdiff_t)trow * DM + col0;
                #pragma unroll
                for (int kk = 0; kk < 2; ++kk) {
                    us8 bv = *(const us8*)(bp + kk * 32 + lgrp * 8);
                    g[c] = MFMA16(qvsF[kk], (s8v)bv, g[c]);
                }
            }
        }
        // sheared G store, b64-packed (pitch 20)
        #pragma unroll
        for (int c = 0; c < 5; ++c) {
            int cl = c * 16 + lan16;
            u32x2 pp;
            pp[0] = cvtpk(g[c][0], g[c][1]);
            pp[1] = cvtpk(g[c][2], g[c][3]);
            *(u32x2*)&gw[cl * 20 + lgrp * 4] = pp;
        }
        WAVE_LDS_FENCE();   // G stores -> G reads

        // read ALL G values (region reused for P^T next)
        float gval[16];
        #pragma unroll
        for (int nf = 0; nf < 4; ++nf)
            #pragma unroll
            for (int rg = 0; rg < 4; ++rg) {
                const int rhat = lgrp * 4 + rg;
                gval[nf * 4 + rg] = bf2f(gw[(nf * 16 + lan16 - rhat + 15) * 20 + rhat]);
            }
        WAVE_LDS_FENCE();   // all G reads done before P^T overwrites region

        // fixed-max softmax; P^T[jl][rhat] into the same GP region (pitch 20)
        #pragma unroll
        for (int nf = 0; nf < 4; ++nf) {
            int jl = nf * 16 + lan16;
            float pp[4];
            #pragma unroll
            for (int rg = 0; rg < 4; ++rg) {
                pp[rg] = exp2f(fmaf(acF[nf][rg] + gval[nf * 4 + rg], C1, C0));
                lsum[rg] += pp[rg];
            }
            u32x2 pk;
            pk[0] = cvtpk(pp[0], pp[1]);
            pk[1] = cvtpk(pp[2], pp[3]);
            *(u32x2*)&gw[jl * 20 + lgrp * 4] = pk;
        }
        WAVE_LDS_FENCE();   // P stores -> pF gather

        // gather next pFprev (consumed by PV(t) at tile t+1)
        #pragma unroll
        for (int kk = 0; kk < 2; ++kk) {
            us8 tmp;
            #pragma unroll
            for (int e = 0; e < 8; ++e)
                tmp[e] = gw[(kk * 32 + lgrp * 8 + e) * 20 + lan16];
            pFprev[kk] = (s8v)tmp;
        }
        __builtin_amdgcn_sched_barrier(0);
        __builtin_amdgcn_s_barrier();            // B2: all reads of cur bufs done
        __builtin_amdgcn_sched_barrier(0);
        // stage V(t+1) into Vb[cur^1] (its old content consumed above),
        // K/B(t+2) into the buffers just consumed this tile.
        const int tv = (tt < 31) ? tt + 1 : 31;
        const int tn = (tt < 30) ? tt + 2 : 31;
        stageV(tv * 64, cur ^ 1);
        stageK(tn * 64, cur);
        stageB(tn * 64 - i0, cur);
        __builtin_amdgcn_sched_barrier(0);
    };

    #pragma unroll 1
    for (int tp = 0; tp < 16; ++tp) {    // unroll-by-2: cur constant per site
        tile_body(tp * 2, 0);
        tile_body(tp * 2 + 1, 1);
    }

    // epilogue PV(31): pFprev from tile 31, V(31) in Vb[1] (untouched since)
    #pragma unroll
    for (int nf = 0; nf < 4; ++nf)
        #pragma unroll
        for (int kk = 0; kk < 2; ++kk) {
            s8v vF = sw_read8(&Vb[1][0], nf * 16 + lan16, kk * 32 + lgrp * 8);
            accO[nf] = MFMA16(pFprev[kk], vF, accO[nf]);
        }

    // epilogue: full row-sum (DPP over lan16), normalize, store
    #pragma unroll
    for (int rg = 0; rg < 4; ++rg) {
        float s = lsum[rg];
        s += rot16<0x121>(s);
        s += rot16<0x122>(s);
        s += rot16<0x124>(s);
        s += rot16<0x128>(s);
        float inv = 1.f / s;
        const int row = i0 + W + lgrp * 4 + rg;
        #pragma unroll
        for (int nf = 0; nf < 4; ++nf)
            out[(size_t)row * DM + col0 + nf * 16 + lan16] = accO[nf][rg] * inv;
    }
}

// ---------------------------------------------------------------------------
extern "C" void kernel_launch(void* const* d_in, const int* in_sizes, int n_in,
                              void* d_out, int out_size, void* d_ws, size_t ws_size,
                              hipStream_t stream) {
    const float* w  = (const float*)d_in[0];
    const float* Wq = (const float*)d_in[1];
    const float* Wk = (const float*)d_in[2];
    const float* Wv = (const float*)d_in[3];
    const float* Wr = (const float*)d_in[4];
    const float* ub = (const float*)d_in[5];
    const float* vb = (const float*)d_in[6];
    float* out = (float*)d_out;

    const size_t U = 1048576;  // 1M shorts = 2MB
    unsigned short* ws = (unsigned short*)d_ws;
    unsigned short* wbf = ws;            // 2U
    unsigned short* Wqb = ws + 2 * U;
    unsigned short* Wkb = ws + 3 * U;
    unsigned short* Wvb = ws + 4 * U;
    unsigned short* Wrb = ws + 5 * U;
    unsigned short* qb  = ws + 6 * U;    // 2U
    unsigned short* kkb = ws + 8 * U;    // 2U
    unsigned short* vtg = ws + 10 * U;   // 2U (transposed V, [DM][LQ])
    // guarded rp: 128 zero rows + LR rows + 128 zero rows
    unsigned short* rpg = ws + 12 * U + 131072;                 // interior
    unsigned short* r   = rpg + (size_t)LR * DM + 131072;       // sinusoid (4U)

    dim3 blk(256);
    hipLaunchKernelGGL(prep, dim3(11390), blk, 0, stream, w, Wq, Wk, Wv, Wr, wbf, r, rpg);
    hipLaunchKernelGGL(proj_all, dim3(640), blk, 0, stream,
                       wbf, r, Wqb, Wkb, Wvb, Wrb, qb, kkb, vtg, rpg);
    hipLaunchKernelGGL(attn_mfma, dim3(512), blk, 0, stream,
                       qb, kkb, vtg, rpg, ub, vb, out);
}

// Round 16
// 119.015 us; speedup vs baseline: 1.1548x; 1.1016x over previous
//
#include <hip/hip_runtime.h>
#include <math.h>
#include <stddef.h>

#define LQ 2048
#define DM 1024
#define NH 16
#define DH 64
#define LR 4095  // 2*LQ-1

typedef __attribute__((ext_vector_type(4))) float f4v;
typedef __attribute__((ext_vector_type(8))) short s8v;
typedef __attribute__((ext_vector_type(2))) unsigned short us2;
typedef __attribute__((ext_vector_type(8))) unsigned short us8;
typedef __attribute__((ext_vector_type(2))) unsigned int u32x2;
typedef __attribute__((ext_vector_type(4))) unsigned int u32x4;

__device__ __forceinline__ unsigned short f2bf(float x) {
    unsigned int u = __float_as_uint(x);
    return (unsigned short)((u + 0x7FFFu + ((u >> 16) & 1u)) >> 16);
}
__device__ __forceinline__ float bf2f(unsigned short s) {
    return __uint_as_float(((unsigned int)s) << 16);
}
__device__ __forceinline__ unsigned cvtpk(float lo, float hi) {
    unsigned r;
    asm("v_cvt_pk_bf16_f32 %0, %1, %2" : "=v"(r) : "v"(lo), "v"(hi));
    return r;
}
template<int CTRL>
__device__ __forceinline__ float rot16(float x) {
    return __uint_as_float((unsigned)__builtin_amdgcn_update_dpp(
        0, (int)__float_as_uint(x), CTRL, 0xF, 0xF, false));
}
#define GLOAD16(g, l) __builtin_amdgcn_global_load_lds((g), (l), 16, 0, 0)
// fence for cross-lane LDS handoff within a wave (load-bearing! r5 NaN)
#define WAVE_LDS_FENCE() do { \
    asm volatile("s_waitcnt lgkmcnt(0)" ::: "memory"); \
    __builtin_amdgcn_sched_barrier(0); } while (0)

#define MFMA16(a, b, c) __builtin_amdgcn_mfma_f32_16x16x32_bf16((a), (b), (c), 0, 0, 0)

// swizzled read from linear-DMA-staged tile: byte ^= (row&7)<<4 (source was
// pre-swizzled col c8^(row&7), so this recovers global[row][colshort/8])
__device__ __forceinline__ s8v sw_read8(const unsigned short* base, int row, int colshort) {
    int byte = (row * 128 + colshort * 2) ^ ((row & 7) << 4);
    return *(const s8v*)((const char*)base + byte);
}

// ---------------------------------------------------------------------------
// prep: [0,3072) cast f32->bf16 [w|Wq|Wk|Wv|Wr]; [3072,11262) sinusoid r;
// [11262,11390) zero the 128-row guards around rp.
// ---------------------------------------------------------------------------
__global__ __launch_bounds__(256)
void prep(const float* __restrict__ w, const float* __restrict__ Wq,
          const float* __restrict__ Wk, const float* __restrict__ Wv,
          const float* __restrict__ Wr, unsigned short* __restrict__ dst,
          unsigned short* __restrict__ r, unsigned short* __restrict__ rpg) {
    int b = blockIdx.x;
    if (b < 3072) {
        size_t e0 = ((size_t)b * 256 + threadIdx.x) * 8;
        const float* src;
        if (e0 < (size_t)LQ * DM) src = w + e0;
        else {
            size_t ro = e0 - (size_t)LQ * DM;
            int wi = (int)(ro >> 20);
            size_t off = ro & 1048575;
            src = (wi == 0 ? Wq : wi == 1 ? Wk : wi == 2 ? Wv : Wr) + off;
        }
        f4v a = *(const f4v*)src;
        f4v c = *(const f4v*)(src + 4);
        us8 o;
        o[0]=f2bf(a[0]); o[1]=f2bf(a[1]); o[2]=f2bf(a[2]); o[3]=f2bf(a[3]);
        o[4]=f2bf(c[0]); o[5]=f2bf(c[1]); o[6]=f2bf(c[2]); o[7]=f2bf(c[3]);
        *(us8*)(dst + e0) = o;
    } else if (b < 11262) {
        int tg = (b - 3072) * 256 + threadIdx.x;   // LR*512 exactly
        int gm = tg >> 9, c2 = tg & 511;
        float invf = expf(-(float)c2 * (9.210340371976184f / 512.0f));
        float ang = (float)(gm - (LQ - 1)) * invf;
        float sv, cv;
        sincosf(ang, &sv, &cv);
        us2 o; o[0] = f2bf(sv); o[1] = f2bf(cv);
        *(us2*)&r[(size_t)gm * DM + c2 * 2] = o;
    } else {
        int idx = (b - 11262) * 2048 + threadIdx.x * 8;  // [0, 262144)
        unsigned short* p = (idx < 131072)
            ? (rpg - 131072 + idx)
            : (rpg + (size_t)LR * DM + (idx - 131072));
        *(us8*)p = (us8){0,0,0,0,0,0,0,0};
    }
}

// ---------------------------------------------------------------------------
// All 4 projections, 128x128 tile (m97 geometry), BK=64, global_load_lds(16),
// linear LDS, 4 waves each owning a 64x64 quadrant (4x4 frags).
// __launch_bounds__(256,3): cap VGPRs so 3 blocks/CU are co-resident (LDS is
// only 32KB -> occupancy is VGPR-determined; m97's analog sat at ~164 VGPR).
// blocks [0,384): QKV (mat = bid>>7); [384,640): rp (mat=3).
// mat==2 writes C transposed (vt[n][m]) via an LDS-transpose epilogue so the
// global stores are coalesced us8 rows.
// ---------------------------------------------------------------------------
__global__ __launch_bounds__(256, 3)
void proj_all(const unsigned short* __restrict__ wbf, const unsigned short* __restrict__ rr,
              const unsigned short* __restrict__ Wqb, const unsigned short* __restrict__ Wkb,
              const unsigned short* __restrict__ Wvb, const unsigned short* __restrict__ Wrb,
              unsigned short* __restrict__ qb, unsigned short* __restrict__ kkb,
              unsigned short* __restrict__ vtg, unsigned short* __restrict__ rpg) {
    __shared__ unsigned short ldsbuf[2 * 128 * 64];
    unsigned short* As = ldsbuf;
    unsigned short* Bs = ldsbuf + 128 * 64;
    int bid = blockIdx.x;
    int mat, mblk, nblk;
    if (bid < 384) { mat = bid >> 7; int rm = bid & 127; mblk = rm >> 3; nblk = rm & 7; }
    else           { mat = 3; int rm = bid - 384; mblk = rm >> 3; nblk = rm & 7; }
    const int M = (mat < 3) ? LQ : LR;
    const unsigned short* A = (mat < 3) ? wbf : rr;
    const unsigned short* B = mat == 0 ? Wqb : mat == 1 ? Wkb : mat == 2 ? Wvb : Wrb;
    unsigned short* C = mat == 0 ? qb : mat == 1 ? kkb : mat == 2 ? vtg : rpg;
    const int m0 = mblk * 128, n0 = nblk * 128;
    const int t = threadIdx.x;
    const int w = t >> 6, lan16 = t & 15, lgrp = (t & 63) >> 4;
    const int wm = (w >> 1) * 64, wn = (w & 1) * 64;
    f4v acc[4][4] = {};

    for (int k0 = 0; k0 < DM; k0 += 64) {
        #pragma unroll
        for (int it = 0; it < 4; ++it) {
            int slot = it * 256 + t;
            int row = slot >> 3, c8 = slot & 7;
            int gm = m0 + row; if (gm > M - 1) gm = M - 1;
            GLOAD16(A + (size_t)gm * DM + k0 + c8 * 8,
                    (char*)As + (size_t)(it * 256 + (t & ~63)) * 16);
            GLOAD16(B + (size_t)(n0 + row) * DM + k0 + c8 * 8,
                    (char*)Bs + (size_t)(it * 256 + (t & ~63)) * 16);
        }
        __syncthreads();
        #pragma unroll
        for (int kk = 0; kk < 2; ++kk) {
            s8v aF[4], bF[4];
            #pragma unroll
            for (int i = 0; i < 4; ++i) {
                aF[i] = *(const s8v*)&As[(wm + i * 16 + lan16) * 64 + kk * 32 + lgrp * 8];
                bF[i] = *(const s8v*)&Bs[(wn + i * 16 + lan16) * 64 + kk * 32 + lgrp * 8];
            }
            #pragma unroll
            for (int i = 0; i < 4; ++i)
                #pragma unroll
                for (int j = 0; j < 4; ++j)
                    acc[i][j] = MFMA16(aF[i], bF[j], acc[i][j]);
        }
        __syncthreads();
    }
    if (mat != 2) {
        #pragma unroll
        for (int i = 0; i < 4; ++i)
            #pragma unroll
            for (int j = 0; j < 4; ++j)
                #pragma unroll
                for (int rg = 0; rg < 4; ++rg) {
                    int row = m0 + wm + i * 16 + lgrp * 4 + rg;
                    if (row < M)
                        C[(size_t)row * DM + n0 + wn + j * 16 + lan16] = f2bf(acc[i][j][rg]);
                }
    } else {
        // stage C^T in LDS ([128 n][128 m] bf16, byte ^= (n&7)<<4), then
        // coalesced us8 row stores to vt[n][m].
        unsigned short* Ct = ldsbuf;   // reuses As+Bs (dead after last barrier)
        #pragma unroll
        for (int i = 0; i < 4; ++i)
            #pragma unroll
            for (int j = 0; j < 4; ++j) {
                int n = wn + j * 16 + lan16;
                int mb = wm + i * 16 + lgrp * 4;
                int byte = (n * 256 + mb * 2) ^ ((n & 7) << 4);
                u32x2 pp;
                pp[0] = cvtpk(acc[i][j][0], acc[i][j][1]);
                pp[1] = cvtpk(acc[i][j][2], acc[i][j][3]);
                *(u32x2*)((char*)Ct + byte) = pp;
            }
        __syncthreads();
        #pragma unroll
        for (int it = 0; it < 8; ++it) {
            int slot = it * 256 + t;
            int n = slot >> 4, c8 = slot & 15;
            int byte = (n * 256 + c8 * 16) ^ ((n & 7) << 4);
            us8 v = *(const us8*)((const char*)Ct + byte);
            *(us8*)&C[(size_t)(n0 + n) * LQ + m0 + c8 * 8] = v;
        }
    }
}

// ---------------------------------------------------------------------------
// Fused rel-attention with DEFERRED-PV cross-tile pipeline (r15, verified
// 78.9us). Block = (head, 64 q rows), 32 j-tiles. Per tile: one counted
// vmcnt(8) + 2 barriers. PV(t-1) issues right after the top barrier using
// register-carried pFprev and double-buffered Vb (zero memory wait), then
// AC/BD(t) (Kb/Bb staged two tiles ahead). G and P^T share the wave-private
// GP region (read-all-G-first fold). Fixed-max softmax; rel-shift masks via
// zero guard rows around rp. Prologue stages a dummy V so PV(-1) is NaN-safe.
// ---------------------------------------------------------------------------
__global__ __launch_bounds__(256, 2)
void attn_mfma(const unsigned short* __restrict__ q, const unsigned short* __restrict__ kkg,
               const unsigned short* __restrict__ vtg, const unsigned short* __restrict__ rpg,
               const float* __restrict__ ub, const float* __restrict__ vb,
               float* __restrict__ out) {
    __shared__ unsigned short Kb[2][64 * 64];     // 16 KB
    __shared__ unsigned short Bb[2][128 * 64];    // 32 KB
    __shared__ unsigned short Vb[2][64 * 64];     // 16 KB
    __shared__ unsigned short GP[4][80 * 20];     // 12.8 KB (G shear, then P^T)

    // XCD swizzle: 512 = 8 x 64 (2 heads per XCD chunk)
    const int dd = blockIdx.x;
    const int f = (dd & 7) * 64 + (dd >> 3);
    const int h = f >> 5;
    const int i0 = (f & 31) * 64;
    const int col0 = h * DH;

    const int t = threadIdx.x;
    const int w = t >> 6, lan16 = t & 15, lgrp = (t & 63) >> 4;
    const int W = w * 16;
    const int cbase = 48 - W;
    const float C1 = 0.125f * 1.4426950408889634f;
    const float C0 = -4.0f * 1.4426950408889634f;

    unsigned short* gw = GP[w];

    // Q fragments direct from global + f32 bias
    union uv { u32x4 u; s8v s; };
    auto mkfrag = [&](int gi, const float* bias, s8v* dstf) {
        #pragma unroll
        for (int kk = 0; kk < 2; ++kk) {
            int cb = kk * 32 + lgrp * 8;
            us8 qv = (us8){0,0,0,0,0,0,0,0};
            if (gi < LQ) qv = *(const us8*)(q + (size_t)gi * DM + col0 + cb);
            f4v b0 = *(const f4v*)(bias + col0 + cb);
            f4v b1 = *(const f4v*)(bias + col0 + cb + 4);
            uv o;
            o.u[0] = cvtpk(bf2f(qv[0]) + b0[0], bf2f(qv[1]) + b0[1]);
            o.u[1] = cvtpk(bf2f(qv[2]) + b0[2], bf2f(qv[3]) + b0[3]);
            o.u[2] = cvtpk(bf2f(qv[4]) + b1[0], bf2f(qv[5]) + b1[1]);
            o.u[3] = cvtpk(bf2f(qv[6]) + b1[2], bf2f(qv[7]) + b1[3]);
            dstf[kk] = o.s;
        }
    };
    s8v quF[2], qvlF[2], qvsF[2];
    mkfrag(i0 + W + lan16, ub, quF);
    mkfrag(i0 + W + lan16, vb, qvlF);
    mkfrag(i0 + W + 1 + lan16, vb, qvsF);

    // DMA staging: linear LDS dest (wave base + lane*16), pre-swizzled source
    auto stageK = [&](int j0, int buf) {        // 2 VMEM
        #pragma unroll
        for (int it = 0; it < 2; ++it) {
            int slot = it * 256 + t;
            int row = slot >> 3, c8 = (t & 7) ^ (row & 7);
            GLOAD16(kkg + (size_t)(j0 + row) * DM + col0 + c8 * 8,
                    (char*)&Kb[buf][0] + (size_t)(it * 256 + (t & ~63)) * 16);
        }
    };
    auto stageB = [&](int rel, int buf) {       // 4 VMEM
        int base = (rel <= 0) ? rel + 4031 : rel - 65;
        #pragma unroll
        for (int it = 0; it < 4; ++it) {
            int slot = it * 256 + t;
            int row = slot >> 3, c8 = (t & 7) ^ (row & 7);
            GLOAD16(rpg + (ptrdiff_t)(base + row) * DM + col0 + c8 * 8,
                    (char*)&Bb[buf][0] + (size_t)(it * 256 + (t & ~63)) * 16);
        }
    };
    auto stageV = [&](int j0, int buf) {        // 2 VMEM
        #pragma unroll
        for (int it = 0; it < 2; ++it) {
            int slot = it * 256 + t;
            int row = slot >> 3, c8 = (t & 7) ^ (row & 7);
            GLOAD16(vtg + (size_t)(col0 + row) * LQ + j0 + c8 * 8,
                    (char*)&Vb[buf][0] + (size_t)(it * 256 + (t & ~63)) * 16);
        }
    };

    f4v accO[4] = {};
    float lsum[4] = {0.f, 0.f, 0.f, 0.f};
    s8v pFprev[2] = {};   // zero: PV(-1) contributes 0 x (finite dummy V) = 0

    // prologue: K0,B0 | dummyV(buf1) | V0(buf0) | K1,B1  -> 16 VMEM
    stageK(0, 0);
    stageB(0 - i0, 0);
    stageV(0, 1);          // dummy, read by PV(-1) only (weights are zero)
    stageV(0, 0);
    stageK(64, 1);
    stageB(64 - i0, 1);

    // one j-tile; cur = tt&1 is a compile-time constant at each call site
    auto tile_body = [&](int tt, int cur) {
        const int j0 = tt * 64;
        const int rel = j0 - i0;
        __builtin_amdgcn_sched_barrier(0);
        // oldest 8 = {V(t-1...),K(t),B(t)} batch -> staged & landed
        asm volatile("s_waitcnt vmcnt(8)" ::: "memory");
        __builtin_amdgcn_s_barrier();            // B1
        __builtin_amdgcn_sched_barrier(0);

        __builtin_amdgcn_s_setprio(1);
        // PV(t-1): zero memory wait (pFprev in regs, Vb[cur^1] staged long ago)
        #pragma unroll
        for (int nf = 0; nf < 4; ++nf)
            #pragma unroll
            for (int kk = 0; kk < 2; ++kk) {
                s8v vF = sw_read8(&Vb[cur ^ 1][0], nf * 16 + lan16, kk * 32 + lgrp * 8);
                accO[nf] = MFMA16(pFprev[kk], vF, accO[nf]);
            }
        // AC = QU @ K^T
        f4v acF[4] = {};
        #pragma unroll
        for (int nf = 0; nf < 4; ++nf)
            #pragma unroll
            for (int kk = 0; kk < 2; ++kk) {
                s8v bF = sw_read8(&Kb[cur][0], nf * 16 + lan16, kk * 32 + lgrp * 8);
                acF[nf] = MFMA16(quF[kk], bF, acF[nf]);
            }
        // BD: G = QV @ band^T (staged band; guards encode the region mask)
        f4v g[5] = {};
        {
            const s8v* qf = (rel <= 0) ? qvlF : qvsF;
            #pragma unroll
            for (int c = 0; c < 5; ++c)
                #pragma unroll
                for (int kk = 0; kk < 2; ++kk) {
                    s8v bF = sw_read8(&Bb[cur][0], cbase + c * 16 + lan16, kk * 32 + lgrp * 8);
                    g[c] = MFMA16(qf[kk], bF, g[c]);
                }
        }
        __builtin_amdgcn_s_setprio(0);
        if (rel == 0) {   // diag tile: upper band direct from global (once/block)
            #pragma unroll
            for (int c = 0; c < 5; ++c) {
                int trow = -65 + cbase + c * 16 + lan16;
                const unsigned short* bp = rpg + (ptrdiff_t)trow * DM + col0;
                #pragma unroll
                for (int kk = 0; kk < 2; ++kk) {
                    us8 bv = *(const us8*)(bp + kk * 32 + lgrp * 8);
                    g[c] = MFMA16(qvsF[kk], (s8v)bv, g[c]);
                }
            }
        }
        // sheared G store, b64-packed (pitch 20)
        #pragma unroll
        for (int c = 0; c < 5; ++c) {
            int cl = c * 16 + lan16;
            u32x2 pp;
            pp[0] = cvtpk(g[c][0], g[c][1]);
            pp[1] = cvtpk(g[c][2], g[c][3]);
            *(u32x2*)&gw[cl * 20 + lgrp * 4] = pp;
        }
        WAVE_LDS_FENCE();   // G stores -> G reads

        // read ALL G values (region reused for P^T next)
        float gval[16];
        #pragma unroll
        for (int nf = 0; nf < 4; ++nf)
            #pragma unroll
            for (int rg = 0; rg < 4; ++rg) {
                const int rhat = lgrp * 4 + rg;
                gval[nf * 4 + rg] = bf2f(gw[(nf * 16 + lan16 - rhat + 15) * 20 + rhat]);
            }
        WAVE_LDS_FENCE();   // all G reads done before P^T overwrites region

        // fixed-max softmax; P^T[jl][rhat] into the same GP region (pitch 20)
        #pragma unroll
        for (int nf = 0; nf < 4; ++nf) {
            int jl = nf * 16 + lan16;
            float pp[4];
            #pragma unroll
            for (int rg = 0; rg < 4; ++rg) {
                pp[rg] = exp2f(fmaf(acF[nf][rg] + gval[nf * 4 + rg], C1, C0));
                lsum[rg] += pp[rg];
            }
            u32x2 pk;
            pk[0] = cvtpk(pp[0], pp[1]);
            pk[1] = cvtpk(pp[2], pp[3]);
            *(u32x2*)&gw[jl * 20 + lgrp * 4] = pk;
        }
        WAVE_LDS_FENCE();   // P stores -> pF gather

        // gather next pFprev (consumed by PV(t) at tile t+1)
        #pragma unroll
        for (int kk = 0; kk < 2; ++kk) {
            us8 tmp;
            #pragma unroll
            for (int e = 0; e < 8; ++e)
                tmp[e] = gw[(kk * 32 + lgrp * 8 + e) * 20 + lan16];
            pFprev[kk] = (s8v)tmp;
        }
        __builtin_amdgcn_sched_barrier(0);
        __builtin_amdgcn_s_barrier();            // B2: all reads of cur bufs done
        __builtin_amdgcn_sched_barrier(0);
        // stage V(t+1) into Vb[cur^1] (its old content consumed above),
        // K/B(t+2) into the buffers just consumed this tile.
        const int tv = (tt < 31) ? tt + 1 : 31;
        const int tn = (tt < 30) ? tt + 2 : 31;
        stageV(tv * 64, cur ^ 1);
        stageK(tn * 64, cur);
        stageB(tn * 64 - i0, cur);
        __builtin_amdgcn_sched_barrier(0);
    };

    #pragma unroll 1
    for (int tp = 0; tp < 16; ++tp) {    // unroll-by-2: cur constant per site
        tile_body(tp * 2, 0);
        tile_body(tp * 2 + 1, 1);
    }

    // epilogue PV(31): pFprev from tile 31, V(31) in Vb[1] (untouched since)
    #pragma unroll
    for (int nf = 0; nf < 4; ++nf)
        #pragma unroll
        for (int kk = 0; kk < 2; ++kk) {
            s8v vF = sw_read8(&Vb[1][0], nf * 16 + lan16, kk * 32 + lgrp * 8);
            accO[nf] = MFMA16(pFprev[kk], vF, accO[nf]);
        }

    // epilogue: full row-sum (DPP over lan16), normalize, store
    #pragma unroll
    for (int rg = 0; rg < 4; ++rg) {
        float s = lsum[rg];
        s += rot16<0x121>(s);
        s += rot16<0x122>(s);
        s += rot16<0x124>(s);
        s += rot16<0x128>(s);
        float inv = 1.f / s;
        const int row = i0 + W + lgrp * 4 + rg;
        #pragma unroll
        for (int nf = 0; nf < 4; ++nf)
            out[(size_t)row * DM + col0 + nf * 16 + lan16] = accO[nf][rg] * inv;
    }
}

// ---------------------------------------------------------------------------
extern "C" void kernel_launch(void* const* d_in, const int* in_sizes, int n_in,
                              void* d_out, int out_size, void* d_ws, size_t ws_size,
                              hipStream_t stream) {
    const float* w  = (const float*)d_in[0];
    const float* Wq = (const float*)d_in[1];
    const float* Wk = (const float*)d_in[2];
    const float* Wv = (const float*)d_in[3];
    const float* Wr = (const float*)d_in[4];
    const float* ub = (const float*)d_in[5];
    const float* vb = (const float*)d_in[6];
    float* out = (float*)d_out;

    const size_t U = 1048576;  // 1M shorts = 2MB
    unsigned short* ws = (unsigned short*)d_ws;
    unsigned short* wbf = ws;            // 2U
    unsigned short* Wqb = ws + 2 * U;
    unsigned short* Wkb = ws + 3 * U;
    unsigned short* Wvb = ws + 4 * U;
    unsigned short* Wrb = ws + 5 * U;
    unsigned short* qb  = ws + 6 * U;    // 2U
    unsigned short* kkb = ws + 8 * U;    // 2U
    unsigned short* vtg = ws + 10 * U;   // 2U (transposed V, [DM][LQ])
    // guarded rp: 128 zero rows + LR rows + 128 zero rows
    unsigned short* rpg = ws + 12 * U + 131072;                 // interior
    unsigned short* r   = rpg + (size_t)LR * DM + 131072;       // sinusoid (4U)

    dim3 blk(256);
    hipLaunchKernelGGL(prep, dim3(11390), blk, 0, stream, w, Wq, Wk, Wv, Wr, wbf, r, rpg);
    hipLaunchKernelGGL(proj_all, dim3(640), blk, 0, stream,
                       wbf, r, Wqb, Wkb, Wvb, Wrb, qb, kkb, vtg, rpg);
    hipLaunchKernelGGL(attn_mfma, dim3(512), blk, 0, stream,
                       qb, kkb, vtg, rpg, ub, vb, out);
}